// Round 7
// baseline (62.744 us; speedup 1.0000x reference)
//
#include <hip/hip_runtime.h>

constexpr int Bn = 1024;
constexpr int Dn = 64;
constexpr int Cn = 100000;
constexpr int Kn = 5;
constexpr float LOG2E = 1.44269504088896f;
constexpr float LN2   = 0.69314718055994531f;

typedef float f32x4  __attribute__((ext_vector_type(4)));
typedef short bf16x8 __attribute__((ext_vector_type(8)));

__device__ __forceinline__ unsigned short f32_to_bf16(float f) {
  union { float f; unsigned int u; } v; v.f = f;
  unsigned int r = v.u + 0x7FFFu + ((v.u >> 16) & 1u);  // RNE
  return (unsigned short)(r >> 16);
}
__device__ __forceinline__ float bf16_to_f32(unsigned short u) {
  union { unsigned int i; float f; } v; v.i = ((unsigned int)u) << 16; return v.f;
}

// ===================== FUSED MAIN PATH =====================
// r6 geometry (proven 52.5): SPLITS=125/NCH=25, SGRPS=8, 1000 blocks.
// r7 change: write-early staging (regs->LDS at TOP of iter, into idle buf,
// BEFORE compute) + 2-chunk-deep global prefetch. Bank-conflicted writes
// and global latency now overlap the MFMA+exp phase instead of serializing
// at the barrier.
constexpr int SPLITS = 125;
constexpr int CPS    = Cn / SPLITS;   // 800
constexpr int NCH    = CPS / 32;      // 25 chunks of 32 classes
constexpr int SGRPS  = 8;             // 128 samples per block, 32 per wave
constexpr int GRID   = SPLITS * SGRPS; // 1000
constexpr int TP     = 88;            // LDS stride (shorts): 176B, 16B-aligned b128

__global__ __launch_bounds__(256) void fused_gemm_kernel(
    const float* __restrict__ x, const float* __restrict__ W,
    const float* __restrict__ bias, float* __restrict__ P,
    float* __restrict__ out)
{
  __shared__ unsigned short wt[2][32][TP];   // [buf][class][d], 11.3 KB

  const int b   = blockIdx.x;
  const int tid = threadIdx.x;
  if (b == 0 && tid == 0) *out = 0.f;   // replaces memset dispatch

  // Bijective chunked XCD map (nwg=1000 = 8*125): a split's 8 sample-group
  // blocks land on one XCD -> its 204.8KB W slice is HBM-fetched once.
  const int xcd = b & 7, bs = b >> 3;
  const int wgid  = xcd * 125 + bs;
  const int split = wgid >> 3, sgrp = wgid & 7;

  const int lane = tid & 63, wid = tid >> 6;
  const int lr = lane & 15, lg = lane >> 4;
  const int sbase = sgrp * 128 + wid * 32;
  const int cb0   = split * CPS;

  // ---- A-frags: 32 samples/wave, f32 x -> bf16(x*LOG2E) in registers.
  bf16x8 a[2][2];
#pragma unroll
  for (int t = 0; t < 2; ++t) {
    const float* xp = x + (size_t)(sbase + t * 16 + lr) * 64 + lg * 8;
    const float4 v0 = *reinterpret_cast<const float4*>(xp);
    const float4 v1 = *reinterpret_cast<const float4*>(xp + 4);
    const float4 v2 = *reinterpret_cast<const float4*>(xp + 32);
    const float4 v3 = *reinterpret_cast<const float4*>(xp + 36);
    bf16x8 a0, a1;
    a0[0] = (short)f32_to_bf16(v0.x * LOG2E);
    a0[1] = (short)f32_to_bf16(v0.y * LOG2E);
    a0[2] = (short)f32_to_bf16(v0.z * LOG2E);
    a0[3] = (short)f32_to_bf16(v0.w * LOG2E);
    a0[4] = (short)f32_to_bf16(v1.x * LOG2E);
    a0[5] = (short)f32_to_bf16(v1.y * LOG2E);
    a0[6] = (short)f32_to_bf16(v1.z * LOG2E);
    a0[7] = (short)f32_to_bf16(v1.w * LOG2E);
    a1[0] = (short)f32_to_bf16(v2.x * LOG2E);
    a1[1] = (short)f32_to_bf16(v2.y * LOG2E);
    a1[2] = (short)f32_to_bf16(v2.z * LOG2E);
    a1[3] = (short)f32_to_bf16(v2.w * LOG2E);
    a1[4] = (short)f32_to_bf16(v3.x * LOG2E);
    a1[5] = (short)f32_to_bf16(v3.y * LOG2E);
    a1[6] = (short)f32_to_bf16(v3.z * LOG2E);
    a1[7] = (short)f32_to_bf16(v3.w * LOG2E);
    a[t][0] = a0;
    a[t][1] = a1;
  }

  // Staging roles: thread t loads float4 of W rows sd and sd+32 at classes
  // [sc, sc+4). One inst = 8 rows x 128B contiguous segments (aligned).
  const int sd = tid >> 3;          // 0..31
  const int sc = (tid & 7) * 4;     // 0..28
  const float* wrow0 = W + (size_t)sd * Cn;
  const float* wrow1 = W + (size_t)(sd + 32) * Cn;

  // ---- Prologue: stage chunk 0 into LDS[0]; prefetch chunk 1 into regs.
  {
    const float4 v0 = *reinterpret_cast<const float4*>(wrow0 + cb0 + sc);
    const float4 v1 = *reinterpret_cast<const float4*>(wrow1 + cb0 + sc);
#pragma unroll
    for (int j = 0; j < 4; ++j) {
      wt[0][sc + j][sd]      = f32_to_bf16(v0[j]);
      wt[0][sc + j][sd + 32] = f32_to_bf16(v1[j]);
    }
  }
  float4 gA0 = *reinterpret_cast<const float4*>(wrow0 + cb0 + 32 + sc);
  float4 gA1 = *reinterpret_cast<const float4*>(wrow1 + cb0 + 32 + sc);
  __syncthreads();

  float esum[2][4];
#pragma unroll
  for (int t = 0; t < 2; ++t)
#pragma unroll
    for (int j = 0; j < 4; ++j) esum[t][j] = 0.f;

  // ---- Main loop: [issue loads ch+2] [write ch+1 (idle buf)] [compute ch]
  // [barrier]. Writes+loads overlap the MFMA+exp phase; 1 barrier/chunk.
#pragma unroll 1
  for (int ch = 0; ch < NCH; ++ch) {
    float4 gB0, gB1;
    if (ch + 2 < NCH) {
      const int cbn = cb0 + (ch + 2) * 32;
      gB0 = *reinterpret_cast<const float4*>(wrow0 + cbn + sc);
      gB1 = *reinterpret_cast<const float4*>(wrow1 + cbn + sc);
    }
    if (ch + 1 < NCH) {
      const int nb = (ch + 1) & 1;
#pragma unroll
      for (int j = 0; j < 4; ++j) {
        wt[nb][sc + j][sd]      = f32_to_bf16(gA0[j]);
        wt[nb][sc + j][sd + 32] = f32_to_bf16(gA1[j]);
      }
    }

    const int cur = ch & 1;
    const int cb  = cb0 + ch * 32;
    const float bb0 = bias[cb + lr] * LOG2E;
    const float bb1 = bias[cb + 16 + lr] * LOG2E;
    const bf16x8 b00 = *reinterpret_cast<const bf16x8*>(&wt[cur][lr][lg * 8]);
    const bf16x8 b01 = *reinterpret_cast<const bf16x8*>(&wt[cur][lr][32 + lg * 8]);
    const bf16x8 b10 = *reinterpret_cast<const bf16x8*>(&wt[cur][16 + lr][lg * 8]);
    const bf16x8 b11 = *reinterpret_cast<const bf16x8*>(&wt[cur][16 + lr][32 + lg * 8]);

#pragma unroll
    for (int t = 0; t < 2; ++t) {
      f32x4 acc0 = {bb0, bb0, bb0, bb0};
      f32x4 acc1 = {bb1, bb1, bb1, bb1};
      acc0 = __builtin_amdgcn_mfma_f32_16x16x32_bf16(a[t][0], b00, acc0, 0, 0, 0);
      acc1 = __builtin_amdgcn_mfma_f32_16x16x32_bf16(a[t][0], b10, acc1, 0, 0, 0);
      acc0 = __builtin_amdgcn_mfma_f32_16x16x32_bf16(a[t][1], b01, acc0, 0, 0, 0);
      acc1 = __builtin_amdgcn_mfma_f32_16x16x32_bf16(a[t][1], b11, acc1, 0, 0, 0);
#pragma unroll
      for (int j = 0; j < 4; ++j) {
        const float e0 = __builtin_amdgcn_exp2f(acc0[j]);
        const float e1 = __builtin_amdgcn_exp2f(acc1[j]);
        esum[t][j] += e0 + e1;
      }
    }

    __syncthreads();
    gA0 = gB0;
    gA1 = gB1;
  }

  // ---- Reduce over the 16 lr-lanes (classes), once; P[sample][split].
  float red[2][4];
#pragma unroll
  for (int t = 0; t < 2; ++t)
#pragma unroll
    for (int j = 0; j < 4; ++j) {
      float v = esum[t][j];
      v += __shfl_xor(v, 1, 64);
      v += __shfl_xor(v, 2, 64);
      v += __shfl_xor(v, 4, 64);
      v += __shfl_xor(v, 8, 64);
      red[t][j] = v;
    }
  if (lr == 0) {
#pragma unroll
    for (int t = 0; t < 2; ++t)
#pragma unroll
      for (int j = 0; j < 4; ++j)
        P[(size_t)(sbase + t * 16 + lg * 4 + j) * SPLITS + split] = red[t][j];
  }
}

// Loss: P reduce (coalesced) + positives recomputed from f32 W/x with the
// SAME bf16 rounding expressions as the gemm (log2 domain).
__global__ __launch_bounds__(64) void loss3_kernel(
    const float* __restrict__ x, const int* __restrict__ labels,
    const float* __restrict__ W, const float* __restrict__ bias,
    const float* __restrict__ P, float* __restrict__ out)
{
  const int i = blockIdx.x, lane = threadIdx.x;
  float acc = P[(size_t)i * SPLITS + lane];
  if (lane + 64 < SPLITS) acc += P[(size_t)i * SPLITS + lane + 64];
#pragma unroll
  for (int off = 32; off > 0; off >>= 1) acc += __shfl_xor(acc, off, 64);
  const float Si = acc;

  const float xv = bf16_to_f32(f32_to_bf16(x[i * Dn + lane] * LOG2E));  // == A-frag
  float l2[Kn];
#pragma unroll
  for (int p = 0; p < Kn; ++p) {
    const int c = labels[i * Kn + p];
    const float wv = bf16_to_f32(f32_to_bf16(W[(size_t)lane * Cn + c]));  // == staged W
    float v = xv * wv;
#pragma unroll
    for (int off = 32; off > 0; off >>= 1) v += __shfl_xor(v, off, 64);
    l2[p] = v + bias[c] * LOG2E;    // logit * LOG2E
  }
  if (lane == 0) {
    float Psum = 0.f;
#pragma unroll
    for (int p = 0; p < Kn; ++p) Psum += __builtin_amdgcn_exp2f(l2[p]);
    const float neg = Si - Psum;
    float lsum = 0.f;
#pragma unroll
    for (int p = 0; p < Kn; ++p)
      lsum += __logf(__builtin_amdgcn_exp2f(l2[p]) + neg) - l2[p] * LN2;
    atomicAdd(out, lsum * (1.0f / (float)(Bn * Kn)));
  }
}

// ===================== OLD (round-2) FALLBACK PATH =====================
constexpr int NB  = 128;
constexpr int NPB = (Cn + NB - 1) / NB;
constexpr int NPBpad = 784;

__global__ __launch_bounds__(256) void cvt_x_kernel(
    const float* __restrict__ x, unsigned short* __restrict__ xb)
{
  const int i = (blockIdx.x * 256 + threadIdx.x) * 4;
  const float4 v = *reinterpret_cast<const float4*>(x + i);
  ushort4 o;
  o.x = f32_to_bf16(v.x); o.y = f32_to_bf16(v.y);
  o.z = f32_to_bf16(v.z); o.w = f32_to_bf16(v.w);
  *reinterpret_cast<ushort4*>(xb + i) = o;
}

__global__ __launch_bounds__(256) void expsum_mfma_kernel(
    const unsigned short* __restrict__ xb, const float* __restrict__ W,
    const float* __restrict__ bias, float* __restrict__ P,
    float* __restrict__ S, int use_partials)
{
  __shared__ float S_lds[4][Bn];
  const int tid  = threadIdx.x;
  const int lane = tid & 63, wid = tid >> 6;
  const int lg = lane >> 4, lr = lane & 15;
  const int cbase = blockIdx.x * NB + wid * 32;

  for (int i = tid; i < 4 * Bn; i += 256) (&S_lds[0][0])[i] = 0.f;

  bf16x8 bfrag[2][2];
  float  bval[2];
#pragma unroll
  for (int t = 0; t < 2; ++t) {
    const int c  = cbase + t * 16 + lr;
    const bool ok = (c < Cn);
    bval[t] = ok ? bias[c] * LOG2E : -1e38f;
#pragma unroll
    for (int h = 0; h < 2; ++h) {
      bf16x8 bf;
#pragma unroll
      for (int j = 0; j < 8; ++j) {
        const int d = h * 32 + lg * 8 + j;
        const float w = ok ? W[(size_t)d * Cn + c] : 0.f;
        bf[j] = (short)f32_to_bf16(w);
      }
      bfrag[t][h] = bf;
    }
  }
  __syncthreads();

#pragma unroll 1
  for (int ch = 0; ch < Bn / 16; ++ch) {
    const int s = ch * 16 + lr;
    const bf16x8 a0 = *reinterpret_cast<const bf16x8*>(xb + (size_t)s * Dn + lg * 8);
    const bf16x8 a1 = *reinterpret_cast<const bf16x8*>(xb + (size_t)s * Dn + 32 + lg * 8);
    f32x4 acc0 = {0.f, 0.f, 0.f, 0.f};
    f32x4 acc1 = {0.f, 0.f, 0.f, 0.f};
    acc0 = __builtin_amdgcn_mfma_f32_16x16x32_bf16(a0, bfrag[0][0], acc0, 0, 0, 0);
    acc1 = __builtin_amdgcn_mfma_f32_16x16x32_bf16(a0, bfrag[1][0], acc1, 0, 0, 0);
    acc0 = __builtin_amdgcn_mfma_f32_16x16x32_bf16(a1, bfrag[0][1], acc0, 0, 0, 0);
    acc1 = __builtin_amdgcn_mfma_f32_16x16x32_bf16(a1, bfrag[1][1], acc1, 0, 0, 0);

    float v[4];
#pragma unroll
    for (int j = 0; j < 4; ++j) {
      const float e0 = __builtin_amdgcn_exp2f(fmaf(acc0[j], LOG2E, bval[0]));
      const float e1 = __builtin_amdgcn_exp2f(fmaf(acc1[j], LOG2E, bval[1]));
      v[j] = e0 + e1;
    }
#pragma unroll
    for (int j = 0; j < 4; ++j) {
      v[j] += __shfl_xor(v[j], 1, 64);
      v[j] += __shfl_xor(v[j], 2, 64);
      v[j] += __shfl_xor(v[j], 4, 64);
      v[j] += __shfl_xor(v[j], 8, 64);
    }
    if (lr == 0) {
#pragma unroll
      for (int j = 0; j < 4; ++j)
        S_lds[wid][ch * 16 + lg * 4 + j] += v[j];
    }
  }
  __syncthreads();

  if (use_partials) {
    for (int s2 = tid; s2 < Bn; s2 += 256) {
      const float v = S_lds[0][s2] + S_lds[1][s2] + S_lds[2][s2] + S_lds[3][s2];
      P[(size_t)s2 * NPBpad + blockIdx.x] = v;
    }
  } else {
    for (int s2 = tid; s2 < Bn; s2 += 256) {
      const float v = S_lds[0][s2] + S_lds[1][s2] + S_lds[2][s2] + S_lds[3][s2];
      atomicAdd(&S[s2], v);
    }
  }
}

__global__ __launch_bounds__(64) void loss_kernel(
    const float* __restrict__ x, const int* __restrict__ labels,
    const float* __restrict__ W, const float* __restrict__ bias,
    const float* __restrict__ P, const float* __restrict__ S,
    float* __restrict__ out, int use_partials)
{
  const int i    = blockIdx.x;
  const int lane = threadIdx.x;

  float Si;
  if (use_partials) {
    float acc = 0.f;
    for (int j = lane; j < NPB; j += 64) acc += P[(size_t)i * NPBpad + j];
#pragma unroll
    for (int off = 32; off > 0; off >>= 1) acc += __shfl_xor(acc, off, 64);
    Si = acc;
  } else {
    Si = S[i];
  }

  const float xv = x[i * Dn + lane];
  float l[Kn];
#pragma unroll
  for (int p = 0; p < Kn; ++p) {
    const int c = labels[i * Kn + p];
    float v = xv * W[(size_t)lane * Cn + c];
#pragma unroll
    for (int off = 32; off > 0; off >>= 1) v += __shfl_xor(v, off, 64);
    l[p] = v + bias[c];
  }

  if (lane == 0) {
    float Psum = 0.f;
#pragma unroll
    for (int p = 0; p < Kn; ++p) Psum += __expf(l[p]);
    const float neg = Si - Psum;
    float lsum = 0.f;
#pragma unroll
    for (int p = 0; p < Kn; ++p)
      lsum += __logf(__expf(l[p]) + neg) - l[p];
    atomicAdd(out, lsum * (1.0f / (float)(Bn * Kn)));
  }
}

// ===================== launch =====================
extern "C" void kernel_launch(void* const* d_in, const int* in_sizes, int n_in,
                              void* d_out, int out_size, void* d_ws, size_t ws_size,
                              hipStream_t stream) {
  const float* x      = (const float*)d_in[0];
  const int*   labels = (const int*)d_in[1];
  const float* W      = (const float*)d_in[2];
  const float* bias   = (const float*)d_in[3];
  float*       out    = (float*)d_out;
  char*        ws     = (char*)d_ws;

  // Fused-path ws layout: P[512000) only.
  const size_t need_new = (size_t)SPLITS * Bn * 4;   // 512000

  if (ws_size >= need_new) {
    float* P = (float*)ws;
    fused_gemm_kernel<<<GRID, 256, 0, stream>>>(x, W, bias, P, out);
    loss3_kernel<<<Bn, 64, 0, stream>>>(x, labels, W, bias, P, out);
    return;
  }

  // Fallback: round-2 path.
  hipMemsetAsync(out, 0, sizeof(float), stream);
  float*          Sg = (float*)ws;
  unsigned short* xb = (unsigned short*)(ws + 4096);
  float*          Pp = (float*)(ws + 4096 + (size_t)Bn * Dn * 2);
  const size_t need_old = 4096 + (size_t)Bn * Dn * 2 + (size_t)Bn * NPBpad * 4;
  const int use_partials = (ws_size >= need_old) ? 1 : 0;
  if (!use_partials) hipMemsetAsync(Sg, 0, Bn * sizeof(float), stream);

  cvt_x_kernel<<<(Bn * Dn) / (256 * 4), 256, 0, stream>>>(x, xb);
  expsum_mfma_kernel<<<NPB, 256, 0, stream>>>(xb, W, bias, Pp, Sg, use_partials);
  loss_kernel<<<Bn, 64, 0, stream>>>(x, labels, W, bias, Pp, Sg, out, use_partials);
}